// Round 16
// baseline (149.405 us; speedup 1.0000x reference)
//
#include <hip/hip_runtime.h>

typedef unsigned short u16;
typedef unsigned int   u32;
typedef __bf16  bf16x8 __attribute__((ext_vector_type(8)));
typedef float   f32x16 __attribute__((ext_vector_type(16)));
typedef u32     u32x4  __attribute__((ext_vector_type(4)));

#define NN  4096
#define CCH 64
#define CQ  32
#define K1S 0.0225421092623961f   // log2(e)/64  (folded into q)

__device__ __forceinline__ u16 bfc(float a) { return __builtin_bit_cast(u16, (__bf16)a); }

// exp2 pair -> packed bf16x2, accumulating the f32 sum (softmax denom)
__device__ __forceinline__ u32 e2pk_s(float a, float b, float& ps) {
  float ea, eb; u32 r;
  asm("v_exp_f32 %0, %1" : "=v"(ea) : "v"(a));
  asm("v_exp_f32 %0, %1" : "=v"(eb) : "v"(b));
  ps += ea + eb;
  asm("v_cvt_pk_bf16_f32 %0, %1, %2" : "=v"(r) : "v"(ea), "v"(eb));
  return r;
}

// Image layouts (per 64-key chunk), frag-major: every fragment is a coalesced
// 16B/lane load (lane-linear within its 1KB region):
//  K image 4KB: frag f (1KB); lane l=h*32+r31 holds K[key=(f>>1)*32+r31][ck=(f&1)*16+8h+{0..7}]
//  V image 8KB: frag r (1KB); lane l holds V[c=(r&1)*32+r31][key=(r>>2)*32+((r>>1)&1)*16+4h+{0..3,8..11}]

// ---- kernel 1: 1x1 convs; x tile staged ONCE in LDS.
//      Block swizzle: b = bid&7 -> batch-b images written on XCD b, the same
//      XCD attn reads them from (L2-local, 768KB/batch << 4MB).
__global__ __launch_bounds__(512) void qkv_kernel(
    const float* __restrict__ x,
    const float* __restrict__ wq, const float* __restrict__ bq,
    const float* __restrict__ wk, const float* __restrict__ bk,
    const float* __restrict__ wv, const float* __restrict__ bv,
    u16* __restrict__ qT, char* __restrict__ kws, char* __restrict__ vws)
{
  __shared__ float xs[64][64];
  __shared__ u16 qls[64][34];
  __shared__ u16 kls[64][34];
  __shared__ u16 vls[64][66];
  const int bid = blockIdx.x;
  const int b = bid & 7;
  const int chunk = bid >> 3;
  const int nbase = chunk * 64;
  const int t = threadIdx.x, lane = t & 63, wid = t >> 6;

  {
    const float* xb = x + (size_t)b * CCH * NN + nbase;
    const int row = t >> 3, colq = (t & 7) * 2;
    float4 v0 = *(const float4*)(xb + (size_t)row * NN + colq * 4);
    float4 v1 = *(const float4*)(xb + (size_t)row * NN + colq * 4 + 4);
    float4* dst = (float4*)&xs[0][0];
    dst[row * 16 + colq]     = v0;
    dst[row * 16 + colq + 1] = v1;
  }
  __syncthreads();

  float xcol[64];
  #pragma unroll
  for (int c = 0; c < 64; ++c) xcol[c] = xs[c][lane];

  const float* w; const float* bias; float sc = 1.0f;
  const int sub = (wid & 1) * 16;
  if (wid < 2)      { w = wq + sub * 64; bias = bq + sub; sc = K1S; }
  else if (wid < 4) { w = wk + sub * 64; bias = bk + sub; }
  else              { w = wv + (wid - 4) * 16 * 64; bias = bv + (wid - 4) * 16; }

  #pragma unroll 2
  for (int i = 0; i < 16; ++i) {
    float a = bias[i];
    #pragma unroll
    for (int c = 0; c < 64; ++c) a = fmaf(w[i * 64 + c], xcol[c], a);
    a *= sc;
    u16 hv = bfc(a);
    if (wid < 2)      qls[lane][sub + i] = hv;
    else if (wid < 4) kls[lane][sub + i] = hv;
    else              vls[(wid - 4) * 16 + i][lane] = hv;
  }
  __syncthreads();

  u32* qdst = (u32*)(qT + ((size_t)b * NN + nbase) * CQ);
  #pragma unroll
  for (int jj = 0; jj < 2; ++jj) {
    int i = t + 512 * jj;
    int n = i >> 4, cp = i & 15;
    qdst[i] = *(const u32*)&qls[n][cp * 2];
  }
  u32* kimg = (u32*)(kws + ((size_t)b * 64 + chunk) * 4096);
  #pragma unroll
  for (int jj = 0; jj < 2; ++jj) {
    int i = t + 512 * jj;
    int reg = i >> 8, l = (i >> 2) & 63, j2 = i & 3;
    int s = reg >> 1, ks = reg & 1;
    int key = s * 32 + (l & 31);
    int ck  = ks * 16 + (l >> 5) * 8 + j2 * 2;
    kimg[i] = *(const u32*)&kls[key][ck];
  }
  u32* vimg = (u32*)(vws + ((size_t)b * 64 + chunk) * 8192);
  #pragma unroll
  for (int jj = 0; jj < 4; ++jj) {
    int i = t + 512 * jj;
    int reg = i >> 8, l = (i >> 2) & 63, j2 = i & 3;
    int s = reg >> 2, kb = (reg >> 1) & 1, ct = reg & 1;
    int c   = ct * 32 + (l & 31);
    int key = s * 32 + kb * 16 + (l >> 5) * 4 + (j2 >> 1) * 8 + (j2 & 1) * 2;
    vimg[i] = *(const u32*)&vls[c][key];
  }
}

// ---- kernel 2: flash attention; NO LDS, NO barriers. 64 queries/wave,
//      single-banked register streaming of K/V straight from the images.
//      grid MUST be 128*NSPLIT (b:3 bits, qt:4 bits, split:bid>>7).
template<int NSPLIT>
__global__ __launch_bounds__(256, 3) void attn_kernel(
    const u16* __restrict__ qT, const char* __restrict__ kws, const char* __restrict__ vws,
    u32* __restrict__ opart, float* __restrict__ lpart)
{
  constexpr int CH = 64 / NSPLIT;   // 64-key chunks per split
  const int bid = blockIdx.x;
  const int b = bid & 7, qt = (bid >> 3) & 15, split = bid >> 7;  // qt: 256-query tile
  const int t = threadIdx.x, lane = t & 63, wid = t >> 6;
  const int h = lane >> 5, c31 = lane & 31;

  // wave covers queries [qt*256 + wid*64, +64): tiles A (+0) and B (+32)
  const u16* qpA = qT + ((size_t)b * NN + qt * 256 + wid * 64 + c31) * CQ + h * 8;
  const bf16x8 qfA0 = *(const bf16x8*)(qpA);
  const bf16x8 qfA1 = *(const bf16x8*)(qpA + 16);
  const bf16x8 qfB0 = *(const bf16x8*)(qpA + 32 * CQ);
  const bf16x8 qfB1 = *(const bf16x8*)(qpA + 32 * CQ + 16);

  const char* kcb = kws + ((size_t)b * 64 + split * CH) * 4096 + lane * 16;
  const char* vcb = vws + ((size_t)b * 64 + split * CH) * 8192 + lane * 16;

  f32x16 accA0 = {}, accA1 = {}, accB0 = {}, accB1 = {};
  float lsumA = 0.f, lsumB = 0.f;

  for (int c = 0; c < CH; ++c) {
    const char* kp = kcb + (size_t)c * 4096;
    const char* vp = vcb + (size_t)c * 8192;

    // K frags (16 regs, die after S_B)
    const bf16x8 K0 = *(const bf16x8*)(kp);
    const bf16x8 K1 = *(const bf16x8*)(kp + 1024);
    const bf16x8 K2 = *(const bf16x8*)(kp + 2048);
    const bf16x8 K3 = *(const bf16x8*)(kp + 3072);

    u32 pwA[16] __attribute__((aligned(16)));
    u32 pwB[16] __attribute__((aligned(16)));

    // S_A -> exp_A (S_A dies before S_B built)
    {
      f32x16 s0, s1;
      __builtin_amdgcn_s_setprio(1);
      s0 = __builtin_amdgcn_mfma_f32_32x32x16_bf16(K0, qfA0, (f32x16){}, 0, 0, 0);
      s0 = __builtin_amdgcn_mfma_f32_32x32x16_bf16(K1, qfA1, s0, 0, 0, 0);
      s1 = __builtin_amdgcn_mfma_f32_32x32x16_bf16(K2, qfA0, (f32x16){}, 0, 0, 0);
      s1 = __builtin_amdgcn_mfma_f32_32x32x16_bf16(K3, qfA1, s1, 0, 0, 0);
      __builtin_amdgcn_s_setprio(0);
      #pragma unroll
      for (int r = 0; r < 16; r += 2) {
        pwA[r >> 1]       = e2pk_s(s0[r], s0[r + 1], lsumA);
        pwA[8 + (r >> 1)] = e2pk_s(s1[r], s1[r + 1], lsumA);
      }
    }
    // S_B -> exp_B (K dies after)
    {
      f32x16 s0, s1;
      __builtin_amdgcn_s_setprio(1);
      s0 = __builtin_amdgcn_mfma_f32_32x32x16_bf16(K0, qfB0, (f32x16){}, 0, 0, 0);
      s0 = __builtin_amdgcn_mfma_f32_32x32x16_bf16(K1, qfB1, s0, 0, 0, 0);
      s1 = __builtin_amdgcn_mfma_f32_32x32x16_bf16(K2, qfB0, (f32x16){}, 0, 0, 0);
      s1 = __builtin_amdgcn_mfma_f32_32x32x16_bf16(K3, qfB1, s1, 0, 0, 0);
      __builtin_amdgcn_s_setprio(0);
      #pragma unroll
      for (int r = 0; r < 16; r += 2) {
        pwB[r >> 1]       = e2pk_s(s0[r], s0[r + 1], lsumB);
        pwB[8 + (r >> 1)] = e2pk_s(s1[r], s1[r + 1], lsumB);
      }
    }

    // V frags loaded once (32 regs), reused by both q-tiles
    const bf16x8 V0 = *(const bf16x8*)(vp);
    const bf16x8 V1 = *(const bf16x8*)(vp + 1024);
    const bf16x8 V2 = *(const bf16x8*)(vp + 2048);
    const bf16x8 V3 = *(const bf16x8*)(vp + 3072);
    const bf16x8 V4 = *(const bf16x8*)(vp + 4096);
    const bf16x8 V5 = *(const bf16x8*)(vp + 5120);
    const bf16x8 V6 = *(const bf16x8*)(vp + 6144);
    const bf16x8 V7 = *(const bf16x8*)(vp + 7168);

    __builtin_amdgcn_s_setprio(1);
    {
      bf16x8 pf;
      pf = __builtin_bit_cast(bf16x8, *(const u32x4*)&pwA[0]);
      accA0 = __builtin_amdgcn_mfma_f32_32x32x16_bf16(V0, pf, accA0, 0, 0, 0);
      accA1 = __builtin_amdgcn_mfma_f32_32x32x16_bf16(V1, pf, accA1, 0, 0, 0);
      pf = __builtin_bit_cast(bf16x8, *(const u32x4*)&pwA[4]);
      accA0 = __builtin_amdgcn_mfma_f32_32x32x16_bf16(V2, pf, accA0, 0, 0, 0);
      accA1 = __builtin_amdgcn_mfma_f32_32x32x16_bf16(V3, pf, accA1, 0, 0, 0);
      pf = __builtin_bit_cast(bf16x8, *(const u32x4*)&pwA[8]);
      accA0 = __builtin_amdgcn_mfma_f32_32x32x16_bf16(V4, pf, accA0, 0, 0, 0);
      accA1 = __builtin_amdgcn_mfma_f32_32x32x16_bf16(V5, pf, accA1, 0, 0, 0);
      pf = __builtin_bit_cast(bf16x8, *(const u32x4*)&pwA[12]);
      accA0 = __builtin_amdgcn_mfma_f32_32x32x16_bf16(V6, pf, accA0, 0, 0, 0);
      accA1 = __builtin_amdgcn_mfma_f32_32x32x16_bf16(V7, pf, accA1, 0, 0, 0);
      // B tile
      pf = __builtin_bit_cast(bf16x8, *(const u32x4*)&pwB[0]);
      accB0 = __builtin_amdgcn_mfma_f32_32x32x16_bf16(V0, pf, accB0, 0, 0, 0);
      accB1 = __builtin_amdgcn_mfma_f32_32x32x16_bf16(V1, pf, accB1, 0, 0, 0);
      pf = __builtin_bit_cast(bf16x8, *(const u32x4*)&pwB[4]);
      accB0 = __builtin_amdgcn_mfma_f32_32x32x16_bf16(V2, pf, accB0, 0, 0, 0);
      accB1 = __builtin_amdgcn_mfma_f32_32x32x16_bf16(V3, pf, accB1, 0, 0, 0);
      pf = __builtin_bit_cast(bf16x8, *(const u32x4*)&pwB[8]);
      accB0 = __builtin_amdgcn_mfma_f32_32x32x16_bf16(V4, pf, accB0, 0, 0, 0);
      accB1 = __builtin_amdgcn_mfma_f32_32x32x16_bf16(V5, pf, accB1, 0, 0, 0);
      pf = __builtin_bit_cast(bf16x8, *(const u32x4*)&pwB[12]);
      accB0 = __builtin_amdgcn_mfma_f32_32x32x16_bf16(V6, pf, accB0, 0, 0, 0);
      accB1 = __builtin_amdgcn_mfma_f32_32x32x16_bf16(V7, pf, accB1, 0, 0, 0);
    }
    __builtin_amdgcn_s_setprio(0);
  }

  // complete per-query softmax denominators (mirror half of key rows)
  lsumA += __shfl_xor(lsumA, 32, 64);
  lsumB += __shfl_xor(lsumB, 32, 64);

  // opart[(b,qt128)*NSPLIT+split][cp(32)][q(128)], bf16-packed channel pairs
  const int qt128 = qt * 2 + (wid >> 1);
  const size_t obase = ((size_t)(b * 32 + qt128) * NSPLIT + split) * 4096;
  #pragma unroll
  for (int j = 0; j < 2; ++j) {
    const int col = (wid & 1) * 64 + j * 32 + c31;
    #pragma unroll
    for (int ct = 0; ct < 2; ++ct) {
      const f32x16& a = j ? (ct ? accB1 : accB0) : (ct ? accA1 : accA0);
      #pragma unroll
      for (int g2 = 0; g2 < 4; ++g2) {
        #pragma unroll
        for (int b2 = 0; b2 < 2; ++b2) {
          int cp = ct * 16 + g2 * 4 + h * 2 + b2;
          float lo = a[g2 * 4 + b2 * 2], hi = a[g2 * 4 + b2 * 2 + 1];
          u32 pr; asm("v_cvt_pk_bf16_f32 %0, %1, %2" : "=v"(pr) : "v"(lo), "v"(hi));
          opart[obase + cp * 128 + col] = pr;
        }
      }
    }
    if (h == 0)
      lpart[((size_t)(b * 32 + qt128) * NSPLIT + split) * 128 + col] = j ? lsumB : lsumA;
  }
}

// ---- kernel 3: combine splits + normalize + fused final conv + residual
template<int NSPLIT>
__global__ __launch_bounds__(512) void combine_kernel(
    const u32* __restrict__ opart, const float* __restrict__ lpart,
    const float* __restrict__ x, const float* __restrict__ wf, const float* __restrict__ bfb,
    const float* __restrict__ gamma, float* __restrict__ out)
{
  __shared__ float ols[64][65];
  __shared__ float linv[64];
  const int bid = blockIdx.x;
  const int b = bid & 7, qt64 = bid >> 3;
  const int qt128 = qt64 >> 1, qh = qt64 & 1;
  const int t = threadIdx.x, lane = t & 63, wid = t >> 6;

  const u32* ob = opart + (size_t)(b * 32 + qt128) * NSPLIT * 4096 + qh * 64;
  #pragma unroll
  for (int jj = 0; jj < 4; ++jj) {
    int i = t + 512 * jj;
    int cp = i >> 6, q = i & 63;
    float lo = 0.f, hi = 0.f;
    #pragma unroll
    for (int s = 0; s < NSPLIT; ++s) {
      u32 a = ob[s * 4096 + cp * 128 + q];
      lo += __builtin_bit_cast(float, (a << 16));
      hi += __builtin_bit_cast(float, (a & 0xffff0000u));
    }
    ols[cp * 2][q]     = lo;
    ols[cp * 2 + 1][q] = hi;
  }
  if (t < 64) {
    const float* lp = lpart + (size_t)(b * 32 + qt128) * NSPLIT * 128 + qh * 64;
    float l = 0.f;
    #pragma unroll
    for (int s = 0; s < NSPLIT; ++s) l += lp[s * 128 + t];
    linv[t] = 1.f / l;
  }
  __syncthreads();

  const float oinv = linv[lane];
  float oc[64];
  #pragma unroll
  for (int c = 0; c < 64; ++c) oc[c] = ols[c][lane] * oinv;
  const float gm = gamma[0];
  const size_t nidx = (size_t)qt64 * 64 + lane;
  #pragma unroll
  for (int i = 0; i < 8; ++i) {
    const int o = wid * 8 + i;
    float a = bfb[o];
    #pragma unroll
    for (int c = 0; c < 64; ++c) a = fmaf(wf[o * 64 + c], oc[c], a);
    const size_t idx = ((size_t)b * CCH + o) * NN + nidx;
    out[idx] = gm * a + x[idx];
  }
}

extern "C" void kernel_launch(void* const* d_in, const int* in_sizes, int n_in,
                              void* d_out, int out_size, void* d_ws, size_t ws_size,
                              hipStream_t stream) {
  const float* x     = (const float*)d_in[0];
  const float* wq    = (const float*)d_in[1];
  const float* bq    = (const float*)d_in[2];
  const float* wk    = (const float*)d_in[3];
  const float* bk    = (const float*)d_in[4];
  const float* wv    = (const float*)d_in[5];
  const float* bv    = (const float*)d_in[6];
  const float* wf    = (const float*)d_in[7];
  const float* bf_   = (const float*)d_in[8];
  const float* gamma = (const float*)d_in[9];
  float* out = (float*)d_out;

  u16* qT   = (u16*)d_ws;                                   // 2 MB
  char* kws = (char*)(qT + (size_t)8 * NN * CQ);            // 2 MB
  char* vws = kws + (size_t)8 * 64 * 4096;                  // 4 MB
  u32* opart = (u32*)(vws + (size_t)8 * 64 * 8192);
  const size_t base = 2097152ull + 2097152ull + 4194304ull;
  const size_t need8 = base + 8ull * (4194304ull + 131072ull);
  const size_t need4 = base + 4ull * (4194304ull + 131072ull);

  qkv_kernel<<<dim3(512), dim3(512), 0, stream>>>(x, wq, bq, wk, bk, wv, bv, qT, kws, vws);
  if (ws_size >= need8) {
    float* lpart = (float*)(opart + (size_t)8 * 32 * 8 * 4096);
    attn_kernel<8><<<dim3(1024), dim3(256), 0, stream>>>(qT, kws, vws, opart, lpart);   // 128*8
    combine_kernel<8><<<dim3(512), dim3(512), 0, stream>>>(opart, lpart, x, wf, bf_, gamma, out);
  } else if (ws_size >= need4) {
    float* lpart = (float*)(opart + (size_t)8 * 32 * 4 * 4096);
    attn_kernel<4><<<dim3(512), dim3(256), 0, stream>>>(qT, kws, vws, opart, lpart);    // 128*4
    combine_kernel<4><<<dim3(512), dim3(512), 0, stream>>>(opart, lpart, x, wf, bf_, gamma, out);
  } else {
    float* lpart = (float*)(opart + (size_t)8 * 32 * 2 * 4096);
    attn_kernel<2><<<dim3(256), dim3(256), 0, stream>>>(qT, kws, vws, opart, lpart);    // 128*2
    combine_kernel<2><<<dim3(512), dim3(512), 0, stream>>>(opart, lpart, x, wf, bf_, gamma, out);
  }
}

// Round 17
// 93.383 us; speedup vs baseline: 1.5999x; 1.5999x over previous
//
#include <hip/hip_runtime.h>

typedef unsigned short u16;
typedef unsigned int   u32;
typedef __bf16  bf16x8 __attribute__((ext_vector_type(8)));
typedef float   f32x16 __attribute__((ext_vector_type(16)));
typedef u32     u32x4  __attribute__((ext_vector_type(4)));

#define NN  4096
#define CCH 64
#define CQ  32
#define K1S 0.0225421092623961f   // log2(e)/64  (folded into q)

__device__ __forceinline__ u16 bfc(float a) { return __builtin_bit_cast(u16, (__bf16)a); }

// exp2 pair -> packed bf16x2, accumulating the f32 sum (softmax denom)
__device__ __forceinline__ u32 e2pk_s(float a, float b, float& ps) {
  float ea, eb; u32 r;
  asm("v_exp_f32 %0, %1" : "=v"(ea) : "v"(a));
  asm("v_exp_f32 %0, %1" : "=v"(eb) : "v"(b));
  ps += ea + eb;
  asm("v_cvt_pk_bf16_f32 %0, %1, %2" : "=v"(r) : "v"(ea), "v"(eb));
  return r;
}

// Image layouts (per 64-key chunk), frag-major: every fragment is a coalesced
// 16B/lane load (lane-linear within its 1KB region):
//  K image 4KB: frag f (1KB); lane l=h*32+r31 holds K[key=(f>>1)*32+r31][ck=(f&1)*16+8h+{0..7}]
//  V image 8KB: frag r (1KB); lane l holds V[c=(r&1)*32+r31][key=(r>>2)*32+((r>>1)&1)*16+4h+{0..3,8..11}]

// ---- kernel 1: 1x1 convs; x tile staged ONCE in LDS.
//      Block swizzle: b = bid&7 -> batch-b images written on XCD b, the same
//      XCD attn reads them from (L2-local, 768KB/batch << 4MB).
__global__ __launch_bounds__(512) void qkv_kernel(
    const float* __restrict__ x,
    const float* __restrict__ wq, const float* __restrict__ bq,
    const float* __restrict__ wk, const float* __restrict__ bk,
    const float* __restrict__ wv, const float* __restrict__ bv,
    u16* __restrict__ qT, char* __restrict__ kws, char* __restrict__ vws)
{
  __shared__ float xs[64][64];
  __shared__ u16 qls[64][34];
  __shared__ u16 kls[64][34];
  __shared__ u16 vls[64][66];
  const int bid = blockIdx.x;
  const int b = bid & 7;
  const int chunk = bid >> 3;
  const int nbase = chunk * 64;
  const int t = threadIdx.x, lane = t & 63, wid = t >> 6;

  {
    const float* xb = x + (size_t)b * CCH * NN + nbase;
    const int row = t >> 3, colq = (t & 7) * 2;
    float4 v0 = *(const float4*)(xb + (size_t)row * NN + colq * 4);
    float4 v1 = *(const float4*)(xb + (size_t)row * NN + colq * 4 + 4);
    float4* dst = (float4*)&xs[0][0];
    dst[row * 16 + colq]     = v0;
    dst[row * 16 + colq + 1] = v1;
  }
  __syncthreads();

  float xcol[64];
  #pragma unroll
  for (int c = 0; c < 64; ++c) xcol[c] = xs[c][lane];

  const float* w; const float* bias; float sc = 1.0f;
  const int sub = (wid & 1) * 16;
  if (wid < 2)      { w = wq + sub * 64; bias = bq + sub; sc = K1S; }
  else if (wid < 4) { w = wk + sub * 64; bias = bk + sub; }
  else              { w = wv + (wid - 4) * 16 * 64; bias = bv + (wid - 4) * 16; }

  #pragma unroll 2
  for (int i = 0; i < 16; ++i) {
    float a = bias[i];
    #pragma unroll
    for (int c = 0; c < 64; ++c) a = fmaf(w[i * 64 + c], xcol[c], a);
    a *= sc;
    u16 hv = bfc(a);
    if (wid < 2)      qls[lane][sub + i] = hv;
    else if (wid < 4) kls[lane][sub + i] = hv;
    else              vls[(wid - 4) * 16 + i][lane] = hv;
  }
  __syncthreads();

  u32* qdst = (u32*)(qT + ((size_t)b * NN + nbase) * CQ);
  #pragma unroll
  for (int jj = 0; jj < 2; ++jj) {
    int i = t + 512 * jj;
    int n = i >> 4, cp = i & 15;
    qdst[i] = *(const u32*)&qls[n][cp * 2];
  }
  u32* kimg = (u32*)(kws + ((size_t)b * 64 + chunk) * 4096);
  #pragma unroll
  for (int jj = 0; jj < 2; ++jj) {
    int i = t + 512 * jj;
    int reg = i >> 8, l = (i >> 2) & 63, j2 = i & 3;
    int s = reg >> 1, ks = reg & 1;
    int key = s * 32 + (l & 31);
    int ck  = ks * 16 + (l >> 5) * 8 + j2 * 2;
    kimg[i] = *(const u32*)&kls[key][ck];
  }
  u32* vimg = (u32*)(vws + ((size_t)b * 64 + chunk) * 8192);
  #pragma unroll
  for (int jj = 0; jj < 4; ++jj) {
    int i = t + 512 * jj;
    int reg = i >> 8, l = (i >> 2) & 63, j2 = i & 3;
    int s = reg >> 2, kb = (reg >> 1) & 1, ct = reg & 1;
    int c   = ct * 32 + (l & 31);
    int key = s * 32 + kb * 16 + (l >> 5) * 4 + (j2 >> 1) * 8 + (j2 & 1) * 2;
    vimg[i] = *(const u32*)&vls[c][key];
  }
}

// ---- kernel 2: flash attention; NO LDS, NO barriers. 64 queries/wave,
//      single-banked register streaming, all 12 chunk loads issued up front
//      (MLP=12). Natural register budget (2 waves/SIMD) -> no spills.
//      grid MUST be 128*NSPLIT (b:3 bits, qt:4 bits, split:bid>>7).
template<int NSPLIT>
__global__ __launch_bounds__(256, 2) void attn_kernel(
    const u16* __restrict__ qT, const char* __restrict__ kws, const char* __restrict__ vws,
    u32* __restrict__ opart, float* __restrict__ lpart)
{
  constexpr int CH = 64 / NSPLIT;   // 64-key chunks per split
  const int bid = blockIdx.x;
  const int b = bid & 7, qt = (bid >> 3) & 15, split = bid >> 7;  // qt: 256-query tile
  const int t = threadIdx.x, lane = t & 63, wid = t >> 6;
  const int h = lane >> 5, c31 = lane & 31;

  // wave covers queries [qt*256 + wid*64, +64): tiles A (+0) and B (+32)
  const u16* qpA = qT + ((size_t)b * NN + qt * 256 + wid * 64 + c31) * CQ + h * 8;
  const bf16x8 qfA0 = *(const bf16x8*)(qpA);
  const bf16x8 qfA1 = *(const bf16x8*)(qpA + 16);
  const bf16x8 qfB0 = *(const bf16x8*)(qpA + 32 * CQ);
  const bf16x8 qfB1 = *(const bf16x8*)(qpA + 32 * CQ + 16);

  const char* kcb = kws + ((size_t)b * 64 + split * CH) * 4096 + lane * 16;
  const char* vcb = vws + ((size_t)b * 64 + split * CH) * 8192 + lane * 16;

  f32x16 accA0 = {}, accA1 = {}, accB0 = {}, accB1 = {};
  float lsumA = 0.f, lsumB = 0.f;

  for (int c = 0; c < CH; ++c) {
    const char* kp = kcb + (size_t)c * 4096;
    const char* vp = vcb + (size_t)c * 8192;

    // ALL 12 loads of this chunk issued together: K (16 regs) + V (32 regs).
    // V doesn't depend on S -> its latency is covered by S_A/exp_A/S_B/exp_B.
    const bf16x8 K0 = *(const bf16x8*)(kp);
    const bf16x8 K1 = *(const bf16x8*)(kp + 1024);
    const bf16x8 K2 = *(const bf16x8*)(kp + 2048);
    const bf16x8 K3 = *(const bf16x8*)(kp + 3072);
    const bf16x8 V0 = *(const bf16x8*)(vp);
    const bf16x8 V1 = *(const bf16x8*)(vp + 1024);
    const bf16x8 V2 = *(const bf16x8*)(vp + 2048);
    const bf16x8 V3 = *(const bf16x8*)(vp + 3072);
    const bf16x8 V4 = *(const bf16x8*)(vp + 4096);
    const bf16x8 V5 = *(const bf16x8*)(vp + 5120);
    const bf16x8 V6 = *(const bf16x8*)(vp + 6144);
    const bf16x8 V7 = *(const bf16x8*)(vp + 7168);

    u32 pwA[16] __attribute__((aligned(16)));
    u32 pwB[16] __attribute__((aligned(16)));

    // S_A -> exp_A (S_A dies before S_B built)
    {
      f32x16 s0, s1;
      __builtin_amdgcn_s_setprio(1);
      s0 = __builtin_amdgcn_mfma_f32_32x32x16_bf16(K0, qfA0, (f32x16){}, 0, 0, 0);
      s0 = __builtin_amdgcn_mfma_f32_32x32x16_bf16(K1, qfA1, s0, 0, 0, 0);
      s1 = __builtin_amdgcn_mfma_f32_32x32x16_bf16(K2, qfA0, (f32x16){}, 0, 0, 0);
      s1 = __builtin_amdgcn_mfma_f32_32x32x16_bf16(K3, qfA1, s1, 0, 0, 0);
      __builtin_amdgcn_s_setprio(0);
      #pragma unroll
      for (int r = 0; r < 16; r += 2) {
        pwA[r >> 1]       = e2pk_s(s0[r], s0[r + 1], lsumA);
        pwA[8 + (r >> 1)] = e2pk_s(s1[r], s1[r + 1], lsumA);
      }
    }
    // S_B -> exp_B (K dies after)
    {
      f32x16 s0, s1;
      __builtin_amdgcn_s_setprio(1);
      s0 = __builtin_amdgcn_mfma_f32_32x32x16_bf16(K0, qfB0, (f32x16){}, 0, 0, 0);
      s0 = __builtin_amdgcn_mfma_f32_32x32x16_bf16(K1, qfB1, s0, 0, 0, 0);
      s1 = __builtin_amdgcn_mfma_f32_32x32x16_bf16(K2, qfB0, (f32x16){}, 0, 0, 0);
      s1 = __builtin_amdgcn_mfma_f32_32x32x16_bf16(K3, qfB1, s1, 0, 0, 0);
      __builtin_amdgcn_s_setprio(0);
      #pragma unroll
      for (int r = 0; r < 16; r += 2) {
        pwB[r >> 1]       = e2pk_s(s0[r], s0[r + 1], lsumB);
        pwB[8 + (r >> 1)] = e2pk_s(s1[r], s1[r + 1], lsumB);
      }
    }

    __builtin_amdgcn_s_setprio(1);
    {
      bf16x8 pf;
      pf = __builtin_bit_cast(bf16x8, *(const u32x4*)&pwA[0]);
      accA0 = __builtin_amdgcn_mfma_f32_32x32x16_bf16(V0, pf, accA0, 0, 0, 0);
      accA1 = __builtin_amdgcn_mfma_f32_32x32x16_bf16(V1, pf, accA1, 0, 0, 0);
      pf = __builtin_bit_cast(bf16x8, *(const u32x4*)&pwA[4]);
      accA0 = __builtin_amdgcn_mfma_f32_32x32x16_bf16(V2, pf, accA0, 0, 0, 0);
      accA1 = __builtin_amdgcn_mfma_f32_32x32x16_bf16(V3, pf, accA1, 0, 0, 0);
      pf = __builtin_bit_cast(bf16x8, *(const u32x4*)&pwA[8]);
      accA0 = __builtin_amdgcn_mfma_f32_32x32x16_bf16(V4, pf, accA0, 0, 0, 0);
      accA1 = __builtin_amdgcn_mfma_f32_32x32x16_bf16(V5, pf, accA1, 0, 0, 0);
      pf = __builtin_bit_cast(bf16x8, *(const u32x4*)&pwA[12]);
      accA0 = __builtin_amdgcn_mfma_f32_32x32x16_bf16(V6, pf, accA0, 0, 0, 0);
      accA1 = __builtin_amdgcn_mfma_f32_32x32x16_bf16(V7, pf, accA1, 0, 0, 0);
      // B tile
      pf = __builtin_bit_cast(bf16x8, *(const u32x4*)&pwB[0]);
      accB0 = __builtin_amdgcn_mfma_f32_32x32x16_bf16(V0, pf, accB0, 0, 0, 0);
      accB1 = __builtin_amdgcn_mfma_f32_32x32x16_bf16(V1, pf, accB1, 0, 0, 0);
      pf = __builtin_bit_cast(bf16x8, *(const u32x4*)&pwB[4]);
      accB0 = __builtin_amdgcn_mfma_f32_32x32x16_bf16(V2, pf, accB0, 0, 0, 0);
      accB1 = __builtin_amdgcn_mfma_f32_32x32x16_bf16(V3, pf, accB1, 0, 0, 0);
      pf = __builtin_bit_cast(bf16x8, *(const u32x4*)&pwB[8]);
      accB0 = __builtin_amdgcn_mfma_f32_32x32x16_bf16(V4, pf, accB0, 0, 0, 0);
      accB1 = __builtin_amdgcn_mfma_f32_32x32x16_bf16(V5, pf, accB1, 0, 0, 0);
      pf = __builtin_bit_cast(bf16x8, *(const u32x4*)&pwB[12]);
      accB0 = __builtin_amdgcn_mfma_f32_32x32x16_bf16(V6, pf, accB0, 0, 0, 0);
      accB1 = __builtin_amdgcn_mfma_f32_32x32x16_bf16(V7, pf, accB1, 0, 0, 0);
    }
    __builtin_amdgcn_s_setprio(0);
  }

  // complete per-query softmax denominators (mirror half of key rows)
  lsumA += __shfl_xor(lsumA, 32, 64);
  lsumB += __shfl_xor(lsumB, 32, 64);

  // opart[(b,qt128)*NSPLIT+split][cp(32)][q(128)], bf16-packed channel pairs
  const int qt128 = qt * 2 + (wid >> 1);
  const size_t obase = ((size_t)(b * 32 + qt128) * NSPLIT + split) * 4096;
  #pragma unroll
  for (int j = 0; j < 2; ++j) {
    const int col = (wid & 1) * 64 + j * 32 + c31;
    #pragma unroll
    for (int ct = 0; ct < 2; ++ct) {
      const f32x16& a = j ? (ct ? accB1 : accB0) : (ct ? accA1 : accA0);
      #pragma unroll
      for (int g2 = 0; g2 < 4; ++g2) {
        #pragma unroll
        for (int b2 = 0; b2 < 2; ++b2) {
          int cp = ct * 16 + g2 * 4 + h * 2 + b2;
          float lo = a[g2 * 4 + b2 * 2], hi = a[g2 * 4 + b2 * 2 + 1];
          u32 pr; asm("v_cvt_pk_bf16_f32 %0, %1, %2" : "=v"(pr) : "v"(lo), "v"(hi));
          opart[obase + cp * 128 + col] = pr;
        }
      }
    }
    if (h == 0)
      lpart[((size_t)(b * 32 + qt128) * NSPLIT + split) * 128 + col] = j ? lsumB : lsumA;
  }
}

// ---- kernel 3: combine splits + normalize + fused final conv + residual
template<int NSPLIT>
__global__ __launch_bounds__(512) void combine_kernel(
    const u32* __restrict__ opart, const float* __restrict__ lpart,
    const float* __restrict__ x, const float* __restrict__ wf, const float* __restrict__ bfb,
    const float* __restrict__ gamma, float* __restrict__ out)
{
  __shared__ float ols[64][65];
  __shared__ float linv[64];
  const int bid = blockIdx.x;
  const int b = bid & 7, qt64 = bid >> 3;
  const int qt128 = qt64 >> 1, qh = qt64 & 1;
  const int t = threadIdx.x, lane = t & 63, wid = t >> 6;

  const u32* ob = opart + (size_t)(b * 32 + qt128) * NSPLIT * 4096 + qh * 64;
  #pragma unroll
  for (int jj = 0; jj < 4; ++jj) {
    int i = t + 512 * jj;
    int cp = i >> 6, q = i & 63;
    float lo = 0.f, hi = 0.f;
    #pragma unroll
    for (int s = 0; s < NSPLIT; ++s) {
      u32 a = ob[s * 4096 + cp * 128 + q];
      lo += __builtin_bit_cast(float, (a << 16));
      hi += __builtin_bit_cast(float, (a & 0xffff0000u));
    }
    ols[cp * 2][q]     = lo;
    ols[cp * 2 + 1][q] = hi;
  }
  if (t < 64) {
    const float* lp = lpart + (size_t)(b * 32 + qt128) * NSPLIT * 128 + qh * 64;
    float l = 0.f;
    #pragma unroll
    for (int s = 0; s < NSPLIT; ++s) l += lp[s * 128 + t];
    linv[t] = 1.f / l;
  }
  __syncthreads();

  const float oinv = linv[lane];
  float oc[64];
  #pragma unroll
  for (int c = 0; c < 64; ++c) oc[c] = ols[c][lane] * oinv;
  const float gm = gamma[0];
  const size_t nidx = (size_t)qt64 * 64 + lane;
  #pragma unroll
  for (int i = 0; i < 8; ++i) {
    const int o = wid * 8 + i;
    float a = bfb[o];
    #pragma unroll
    for (int c = 0; c < 64; ++c) a = fmaf(wf[o * 64 + c], oc[c], a);
    const size_t idx = ((size_t)b * CCH + o) * NN + nidx;
    out[idx] = gm * a + x[idx];
  }
}

extern "C" void kernel_launch(void* const* d_in, const int* in_sizes, int n_in,
                              void* d_out, int out_size, void* d_ws, size_t ws_size,
                              hipStream_t stream) {
  const float* x     = (const float*)d_in[0];
  const float* wq    = (const float*)d_in[1];
  const float* bq    = (const float*)d_in[2];
  const float* wk    = (const float*)d_in[3];
  const float* bk    = (const float*)d_in[4];
  const float* wv    = (const float*)d_in[5];
  const float* bv    = (const float*)d_in[6];
  const float* wf    = (const float*)d_in[7];
  const float* bf_   = (const float*)d_in[8];
  const float* gamma = (const float*)d_in[9];
  float* out = (float*)d_out;

  u16* qT   = (u16*)d_ws;                                   // 2 MB
  char* kws = (char*)(qT + (size_t)8 * NN * CQ);            // 2 MB
  char* vws = kws + (size_t)8 * 64 * 4096;                  // 4 MB
  u32* opart = (u32*)(vws + (size_t)8 * 64 * 8192);
  const size_t base = 2097152ull + 2097152ull + 4194304ull;
  const size_t need8 = base + 8ull * (4194304ull + 131072ull);
  const size_t need4 = base + 4ull * (4194304ull + 131072ull);

  qkv_kernel<<<dim3(512), dim3(512), 0, stream>>>(x, wq, bq, wk, bk, wv, bv, qT, kws, vws);
  if (ws_size >= need8) {
    float* lpart = (float*)(opart + (size_t)8 * 32 * 8 * 4096);
    attn_kernel<8><<<dim3(1024), dim3(256), 0, stream>>>(qT, kws, vws, opart, lpart);   // 128*8
    combine_kernel<8><<<dim3(512), dim3(512), 0, stream>>>(opart, lpart, x, wf, bf_, gamma, out);
  } else if (ws_size >= need4) {
    float* lpart = (float*)(opart + (size_t)8 * 32 * 4 * 4096);
    attn_kernel<4><<<dim3(512), dim3(256), 0, stream>>>(qT, kws, vws, opart, lpart);    // 128*4
    combine_kernel<4><<<dim3(512), dim3(512), 0, stream>>>(opart, lpart, x, wf, bf_, gamma, out);
  } else {
    float* lpart = (float*)(opart + (size_t)8 * 32 * 2 * 4096);
    attn_kernel<2><<<dim3(256), dim3(256), 0, stream>>>(qT, kws, vws, opart, lpart);    // 128*2
    combine_kernel<2><<<dim3(512), dim3(512), 0, stream>>>(opart, lpart, x, wf, bf_, gamma, out);
  }
}